// Round 2
// baseline (10401.362 us; speedup 1.0000x reference)
//
#include <hip/hip_runtime.h>
#include <hip/hip_bf16.h>
#include <cstdint>
#include <cstddef>

// Problem constants (from reference): P=2048, K=8, T=32, C=16384, F=128
#define PP 2048
#define KK 8
#define TT 32
#define FF 128
#define G3 384  // 3*F gate rows

// Packed-bf16 helpers: u holds two bf16 (low ushort = element 2i, high = 2i+1).
__device__ __forceinline__ float bf16_lo(uint32_t u) {
    union { uint32_t u; float f; } cv; cv.u = u << 16; return cv.f;
}
__device__ __forceinline__ float bf16_hi(uint32_t u) {
    union { uint32_t u; float f; } cv; cv.u = u & 0xffff0000u; return cv.f;
}
__device__ __forceinline__ uint32_t pack_bf16(float a, float b) {
    // round-to-nearest-even via __float2bfloat16 (keeps weight error <= 2^-9 rel)
    union { __hip_bfloat16 h; uint16_t s; } ca, cb;
    ca.h = __float2bfloat16(a);
    cb.h = __float2bfloat16(b);
    return (uint32_t)ca.s | ((uint32_t)cb.s << 16);
}
__device__ __forceinline__ float sigmoid_f(float x) {
    return 1.0f / (1.0f + __expf(-x));
}
__device__ __forceinline__ float tanh_f(float x) {
    float e = __expf(-2.0f * fabsf(x));
    float t = (1.0f - e) / (1.0f + e);
    return copysignf(t, x);
}

// One block per path. 384 threads: thread g owns gate row g (0..127 = r,
// 128..255 = z, 256..383 = n). Weight rows live in VGPRs as packed bf16
// (f32 rows would need 256 VGPRs -> forced spill at 6 waves/block).
// h state is f32 in LDS for the full 256-step recurrence; all math f32.
__global__ __launch_bounds__(384) void gru_path_kernel(
    const float* __restrict__ h0,    // [P, F]
    const float* __restrict__ feat,  // [C, T, F]
    const float* __restrict__ w_ih,  // [3F, F]
    const float* __restrict__ w_hh,  // [3F, F]
    const float* __restrict__ b_ih,  // [3F]
    const float* __restrict__ b_hh,  // [3F]
    const int* __restrict__ idx,     // [P, K]
    float* __restrict__ out)         // [P, F]
{
    const int p = blockIdx.x;
    const int g = threadIdx.x;  // 0..383

    __shared__ __align__(16) float xs[FF];
    __shared__ __align__(16) float hs[FF];
    __shared__ float xacc[G3];
    __shared__ float hacc[G3];
    __shared__ int   cidx[KK];

    // Load this thread's two f32 weight rows, convert to packed bf16:
    // 128 bf16 = 64 uint32 = 16 uint4 per row.
    uint4 wih[16], whh[16];
    {
        const float4* wi = (const float4*)(w_ih + (size_t)g * FF);
        const float4* wh = (const float4*)(w_hh + (size_t)g * FF);
#pragma unroll
        for (int i = 0; i < 16; ++i) {
            float4 a0 = wi[2 * i], a1 = wi[2 * i + 1];
            wih[i] = make_uint4(pack_bf16(a0.x, a0.y), pack_bf16(a0.z, a0.w),
                                pack_bf16(a1.x, a1.y), pack_bf16(a1.z, a1.w));
            float4 b0 = wh[2 * i], b1 = wh[2 * i + 1];
            whh[i] = make_uint4(pack_bf16(b0.x, b0.y), pack_bf16(b0.z, b0.w),
                                pack_bf16(b1.x, b1.y), pack_bf16(b1.z, b1.w));
        }
    }
    const float bi = b_ih[g];
    const float bh = b_hh[g];

    if (g < FF) hs[g] = h0[(size_t)p * FF + g];
    if (g < KK) cidx[g] = idx[p * KK + g];
    __syncthreads();

    for (int k = 0; k < KK; ++k) {
        const float* xb = feat + (size_t)cidx[k] * (TT * FF);
        for (int t = 0; t < TT; ++t) {
            // Stage x_t into LDS (one wave: 128 f32, coalesced 512 B).
            if (g < FF) xs[g] = xb[t * FF + g];
            __syncthreads();

            // Two length-128 dot products per thread; 4 chains for FMA ILP.
            float ax0 = bi, ax1 = 0.f, ah0 = bh, ah1 = 0.f;
            const float4* x4 = (const float4*)xs;
            const float4* h4 = (const float4*)hs;
#pragma unroll
            for (int i = 0; i < 16; ++i) {
                const float4 xv0 = x4[2 * i];
                const float4 xv1 = x4[2 * i + 1];
                const float4 hv0 = h4[2 * i];
                const float4 hv1 = h4[2 * i + 1];
                const uint4 wi = wih[i];
                const uint4 wh = whh[i];
                ax0 += bf16_lo(wi.x) * xv0.x + bf16_hi(wi.x) * xv0.y
                     + bf16_lo(wi.y) * xv0.z + bf16_hi(wi.y) * xv0.w;
                ax1 += bf16_lo(wi.z) * xv1.x + bf16_hi(wi.z) * xv1.y
                     + bf16_lo(wi.w) * xv1.z + bf16_hi(wi.w) * xv1.w;
                ah0 += bf16_lo(wh.x) * hv0.x + bf16_hi(wh.x) * hv0.y
                     + bf16_lo(wh.y) * hv0.z + bf16_hi(wh.y) * hv0.w;
                ah1 += bf16_lo(wh.z) * hv1.x + bf16_hi(wh.z) * hv1.y
                     + bf16_lo(wh.w) * hv1.z + bf16_hi(wh.w) * hv1.w;
            }
            xacc[g] = ax0 + ax1;
            hacc[g] = ah0 + ah1;
            __syncthreads();

            // Gate math + state update (threads 0..127; wave-aligned branch).
            if (g < FF) {
                const float r = sigmoid_f(xacc[g] + hacc[g]);
                const float z = sigmoid_f(xacc[g + FF] + hacc[g + FF]);
                const float n = tanh_f(xacc[g + 2 * FF] + r * hacc[g + 2 * FF]);
                hs[g] = (1.0f - z) * n + z * hs[g];
            }
            __syncthreads();
        }
    }

    if (g < FF) out[(size_t)p * FF + g] = hs[g];
}

extern "C" void kernel_launch(void* const* d_in, const int* in_sizes, int n_in,
                              void* d_out, int out_size, void* d_ws, size_t ws_size,
                              hipStream_t stream) {
    const float* h0   = (const float*)d_in[0];
    const float* feat = (const float*)d_in[1];
    const float* wih  = (const float*)d_in[2];
    const float* whh  = (const float*)d_in[3];
    const float* bih  = (const float*)d_in[4];
    const float* bhh  = (const float*)d_in[5];
    const int*   idx  = (const int*)d_in[6];
    float*       out  = (float*)d_out;

    gru_path_kernel<<<dim3(PP), dim3(G3), 0, stream>>>(
        h0, feat, wih, whh, bih, bhh, idx, out);
}

// Round 3
// 677.004 us; speedup vs baseline: 15.3638x; 15.3638x over previous
//
#include <hip/hip_runtime.h>
#include <hip/hip_bf16.h>
#include <cstdint>
#include <cstddef>

// Problem constants: P=2048, K=8, T=32, C=16384, F=128
#define PP 2048
#define KK 8
#define TT 32
#define FF 128
#define MB 16          // paths per block
#define NBLK (PP/MB)   // 128 blocks
#define NTHR 512       // 8 waves

typedef __attribute__((ext_vector_type(8))) short short8;  // 8 bf16 (4 VGPRs)
typedef __attribute__((ext_vector_type(4))) float f32x4;   // MFMA C/D frag

__device__ __forceinline__ short f2bf(float x) {
    union { __hip_bfloat16 h; short s; } u; u.h = __float2bfloat16(x); return u.s;
}
__device__ __forceinline__ float bf2f(short s) {
    union { uint32_t u; float f; } cv; cv.u = ((uint32_t)(uint16_t)s) << 16; return cv.f;
}
__device__ __forceinline__ float sigmoid_f(float x) { return 1.f / (1.f + __expf(-x)); }
__device__ __forceinline__ float tanh_f(float x) {
    float e = __expf(-2.f * fabsf(x));
    float t = (1.f - e) / (1.f + e);
    return copysignf(t, x);
}

// Block: 16 paths through 256 GRU steps. Per step, per wave w (owns gate
// columns f in [16w,16w+16), i.e. column-tiles {w, w+8, w+16} = r,z,n for the
// same f-range): 36 mfma_f32_16x16x32_bf16. Weights live in VGPRs as
// B-fragments for the whole kernel. h state: f32 master + bf16 hi/lo split
// for MFMA input (keeps 256-step error compounding at f32 level).
// A-fragments staged in LDS in frag-linear order (lane*16B): conflict-free
// ds_read_b128. Double-buffered x/h -> one barrier per step.
__global__ __launch_bounds__(NTHR) void gru_mfma_kernel(
    const float* __restrict__ h0,    // [P, F]
    const float* __restrict__ feat,  // [C, T, F]
    const float* __restrict__ w_ih,  // [3F, F]
    const float* __restrict__ w_hh,  // [3F, F]
    const float* __restrict__ b_ih,  // [3F]
    const float* __restrict__ b_hh,  // [3F]
    const int* __restrict__ idx,     // [P, K]
    float* __restrict__ out)         // [P, F]
{
    const int tid  = threadIdx.x;
    const int w    = tid >> 6;    // wave 0..7
    const int lane = tid & 63;
    const int q    = lane >> 4;   // quad 0..3
    const int nl   = lane & 15;   // col within tile
    const int p0   = blockIdx.x * MB;

    // Frag-linear LDS: [buf][k-chunk][frag-lane][8 bf16]
    __shared__ __align__(16) short xfrag[2][4][64][8];
    __shared__ __align__(16) short hhif[2][4][64][8];
    __shared__ __align__(16) short hlof[2][4][64][8];
    __shared__ __align__(16) float hf32[2][MB][FF];
    __shared__ int cidx_s[MB][KK];

    // ---- B-fragments (weights) resident in VGPRs: wave w needs gate rows
    // g = (w+8*tt)*16 + nl, k = c*32 + q*8 + j. 96 VGPRs total.
    short8 wbi[3][4], wbh[3][4];
#pragma unroll
    for (int tt = 0; tt < 3; ++tt) {
        const int g = (w + 8 * tt) * 16 + nl;
#pragma unroll
        for (int c = 0; c < 4; ++c) {
            const float* wi = w_ih + (size_t)g * FF + c * 32 + q * 8;
            const float* wh = w_hh + (size_t)g * FF + c * 32 + q * 8;
            short8 a, b;
#pragma unroll
            for (int j = 0; j < 8; ++j) { a[j] = f2bf(wi[j]); b[j] = f2bf(wh[j]); }
            wbi[tt][c] = a; wbh[tt][c] = b;
        }
    }
    const float bir = b_ih[w * 16 + nl], biz = b_ih[FF + w * 16 + nl],
                bin_ = b_ih[2 * FF + w * 16 + nl];
    const float bhr = b_hh[w * 16 + nl], bhz = b_hh[FF + w * 16 + nl],
                bhn = b_hh[2 * FF + w * 16 + nl];

    if (tid < MB * KK) cidx_s[tid >> 3][tid & 7] = idx[(p0 + (tid >> 3)) * KK + (tid & 7)];

    // ---- stage h0: thread -> one float4 of one path row
    const int m_ld = tid >> 5;          // path row 0..15
    const int c32  = tid & 31;          // float4 index in row
    const int col0 = c32 * 4;
    const int chunkL = col0 >> 5, qqL = (col0 & 31) >> 3, j0L = col0 & 7;
    const int flL = m_ld + 16 * qqL;
    {
        f32x4 hv = *(const f32x4*)(h0 + (size_t)(p0 + m_ld) * FF + col0);
        *(f32x4*)&hf32[0][m_ld][col0] = hv;
        uint32_t hi01, hi23, lo01, lo23;
        {
            short a0 = f2bf(hv[0]), a1 = f2bf(hv[1]), a2 = f2bf(hv[2]), a3 = f2bf(hv[3]);
            hi01 = (uint32_t)(uint16_t)a0 | ((uint32_t)(uint16_t)a1 << 16);
            hi23 = (uint32_t)(uint16_t)a2 | ((uint32_t)(uint16_t)a3 << 16);
            short b0 = f2bf(hv[0] - bf2f(a0)), b1 = f2bf(hv[1] - bf2f(a1));
            short b2 = f2bf(hv[2] - bf2f(a2)), b3 = f2bf(hv[3] - bf2f(a3));
            lo01 = (uint32_t)(uint16_t)b0 | ((uint32_t)(uint16_t)b1 << 16);
            lo23 = (uint32_t)(uint16_t)b2 | ((uint32_t)(uint16_t)b3 << 16);
        }
        ((uint32_t*)&hhif[0][chunkL][flL][j0L])[0] = hi01;
        ((uint32_t*)&hhif[0][chunkL][flL][j0L])[1] = hi23;
        ((uint32_t*)&hlof[0][chunkL][flL][j0L])[0] = lo01;
        ((uint32_t*)&hlof[0][chunkL][flL][j0L])[1] = lo23;
    }
    __syncthreads();

    // ---- stage x(step 0)
    int ch = cidx_s[m_ld][0];
    {
        f32x4 xv = *(const f32x4*)(feat + (size_t)ch * (TT * FF) + col0);
        uint32_t x01 = (uint32_t)(uint16_t)f2bf(xv[0]) | ((uint32_t)(uint16_t)f2bf(xv[1]) << 16);
        uint32_t x23 = (uint32_t)(uint16_t)f2bf(xv[2]) | ((uint32_t)(uint16_t)f2bf(xv[3]) << 16);
        ((uint32_t*)&xfrag[0][chunkL][flL][j0L])[0] = x01;
        ((uint32_t*)&xfrag[0][chunkL][flL][j0L])[1] = x23;
    }
    __syncthreads();

    // gate-write indices: this lane's feature column f = 16w + nl
    const int fcol = w * 16 + nl;
    const int chF  = w >> 1;
    const int qqF  = 2 * (w & 1) + (nl >> 3);
    const int jF   = nl & 7;

    int cur = 0;
    for (int kk = 0; kk < KK; ++kk) {
        const float* cb = feat + (size_t)ch * (TT * FF);
        for (int t = 0; t < TT; ++t) {
            // prefetch next step's x (independent of recurrence)
            f32x4 xp;
            const bool have = !(kk == KK - 1 && t == TT - 1);
            if (t < TT - 1) {
                xp = *(const f32x4*)(cb + (t + 1) * FF + col0);
            } else if (kk < KK - 1) {
                ch = cidx_s[m_ld][kk + 1];
                xp = *(const f32x4*)(feat + (size_t)ch * (TT * FF) + col0);
            }
            const int nxt = cur ^ 1;

            // A-fragments (conflict-free: lane i reads bytes [16i,16i+16))
            short8 xa[4], hha[4], hla[4];
#pragma unroll
            for (int c = 0; c < 4; ++c) {
                xa[c]  = *(const short8*)&xfrag[cur][c][lane][0];
                hha[c] = *(const short8*)&hhif[cur][c][lane][0];
                hla[c] = *(const short8*)&hlof[cur][c][lane][0];
            }

            f32x4 ax[3], ah[3];
#pragma unroll
            for (int tt = 0; tt < 3; ++tt) {
                f32x4 a = {0.f, 0.f, 0.f, 0.f};
                f32x4 hc = {0.f, 0.f, 0.f, 0.f};
#pragma unroll
                for (int c = 0; c < 4; ++c)
                    a = __builtin_amdgcn_mfma_f32_16x16x32_bf16(xa[c], wbi[tt][c], a, 0, 0, 0);
#pragma unroll
                for (int c = 0; c < 4; ++c)
                    hc = __builtin_amdgcn_mfma_f32_16x16x32_bf16(hha[c], wbh[tt][c], hc, 0, 0, 0);
#pragma unroll
                for (int c = 0; c < 4; ++c)
                    hc = __builtin_amdgcn_mfma_f32_16x16x32_bf16(hla[c], wbh[tt][c], hc, 0, 0, 0);
                ax[tt] = a; ah[tt] = hc;
            }

            // gates + state update; lane owns rows m=4q+r at column fcol
#pragma unroll
            for (int r = 0; r < 4; ++r) {
                const int mrow = q * 4 + r;
                const float xr = ax[0][r] + bir, hr = ah[0][r] + bhr;
                const float xz = ax[1][r] + biz, hz = ah[1][r] + bhz;
                const float xn = ax[2][r] + bin_, hn = ah[2][r] + bhn;
                const float rr = sigmoid_f(xr + hr);
                const float zz = sigmoid_f(xz + hz);
                const float nn = tanh_f(xn + rr * hn);
                const float hold = hf32[cur][mrow][fcol];
                const float hnew = (1.f - zz) * nn + zz * hold;
                hf32[nxt][mrow][fcol] = hnew;
                const short hi = f2bf(hnew);
                const short lo = f2bf(hnew - bf2f(hi));
                hhif[nxt][chF][mrow + 16 * qqF][jF] = hi;
                hlof[nxt][chF][mrow + 16 * qqF][jF] = lo;
            }

            // stage prefetched x into next buffer
            if (have) {
                uint32_t x01 = (uint32_t)(uint16_t)f2bf(xp[0]) | ((uint32_t)(uint16_t)f2bf(xp[1]) << 16);
                uint32_t x23 = (uint32_t)(uint16_t)f2bf(xp[2]) | ((uint32_t)(uint16_t)f2bf(xp[3]) << 16);
                ((uint32_t*)&xfrag[nxt][chunkL][flL][j0L])[0] = x01;
                ((uint32_t*)&xfrag[nxt][chunkL][flL][j0L])[1] = x23;
            }
            __syncthreads();
            cur = nxt;
        }
    }

    // final h is in hf32[cur] (cur == 0 after 256 flips)
    {
        f32x4 hv = *(const f32x4*)&hf32[cur][m_ld][col0];
        *(f32x4*)(out + (size_t)(p0 + m_ld) * FF + col0) = hv;
    }
}

extern "C" void kernel_launch(void* const* d_in, const int* in_sizes, int n_in,
                              void* d_out, int out_size, void* d_ws, size_t ws_size,
                              hipStream_t stream) {
    const float* h0   = (const float*)d_in[0];
    const float* feat = (const float*)d_in[1];
    const float* wih  = (const float*)d_in[2];
    const float* whh  = (const float*)d_in[3];
    const float* bih  = (const float*)d_in[4];
    const float* bhh  = (const float*)d_in[5];
    const int*   idx  = (const int*)d_in[6];
    float*       out  = (float*)d_out;

    gru_mfma_kernel<<<dim3(NBLK), dim3(NTHR), 0, stream>>>(
        h0, feat, wih, whh, bih, bhh, idx, out);
}

// Round 4
// 579.497 us; speedup vs baseline: 17.9489x; 1.1683x over previous
//
#include <hip/hip_runtime.h>
#include <cstdint>
#include <cstddef>

// Problem constants: P=2048, K=8, T=32, C=16384, F=128
#define PP 2048
#define KK 8
#define TT 32
#define FF 128
#define MB 16
#define NBLK (PP/MB)
#define NTHR 512
#define NSTEP (KK*TT)

typedef __attribute__((ext_vector_type(8))) short short8;  // 8 bf16 (4 VGPRs)
typedef __attribute__((ext_vector_type(4))) float f32x4;   // MFMA C/D frag

__device__ __forceinline__ uint32_t fbits(float x){ union{float f;uint32_t u;}c;c.f=x;return c.u; }
__device__ __forceinline__ float bitsf(uint32_t u){ union{uint32_t u;float f;}c;c.u=u;return c.f; }
// two f32 -> packed bf16 pair, TRUNCATION (cheap; hi/lo split absorbs error for h)
__device__ __forceinline__ uint32_t pk_trunc(float a, float b){
    return (fbits(a) >> 16) | (fbits(b) & 0xffff0000u);
}
// round-to-nearest-even bf16 (prologue-only, for weights)
__device__ __forceinline__ short bf_rne(float x){
    uint32_t u = fbits(x);
    return (short)((u + 0x7fffu + ((u >> 16) & 1u)) >> 16);
}
__device__ __forceinline__ float sigm(float x){
    float t = __expf(-x);                    // x->-inf: t=inf -> rcp=0; x->inf: t=0 -> 1
    return __builtin_amdgcn_rcpf(1.f + t);
}
__device__ __forceinline__ float tanh_fast(float x){
    float e = __expf(-2.f * x);              // saturates correctly via inf -> rcp -> 0
    return __builtin_amdgcn_rcpf(1.f + e) * 2.f - 1.f;
}

// Block: 16 paths x 256 GRU steps. 8 waves; wave w owns gate columns
// f in [16w,16w+16) (tiles {w,w+8,w+16} = r,z,n). Weights resident in VGPRs
// as MFMA B-fragments. h f32 master lives in the producing lane's VGPRs
// (same lane produces and consumes each (m,f) every step -> no LDS f32 state).
// Only bf16 hi/lo h-fragments cross waves via LDS, in a sigma-swizzled
// frag-linear layout (slot = q + 4*(r^qq) + 16*qq) so producer b16 scatter
// is ~2-way (free) and consumer ds_read_b128 stays conflict-free.
// x is staged pre-converted into frag layout by all 512 threads with a
// one-step-ahead global prefetch. One barrier per step.
__global__ __launch_bounds__(NTHR, 2) void gru_mfma2(
    const float* __restrict__ h0,    // [P, F]
    const float* __restrict__ feat,  // [C, T, F]
    const float* __restrict__ w_ih,  // [3F, F]
    const float* __restrict__ w_hh,  // [3F, F]
    const float* __restrict__ b_ih,  // [3F]
    const float* __restrict__ b_hh,  // [3F]
    const int* __restrict__ idx,     // [P, K]
    float* __restrict__ out)         // [P, F]
{
    const int tid  = threadIdx.x;
    const int w    = tid >> 6;
    const int lane = tid & 63;
    const int q    = lane >> 4;
    const int nl   = lane & 15;
    const int p0   = blockIdx.x * MB;

    __shared__ __align__(16) short xfr[2][4][64][8];  // x frags (identity slots)
    __shared__ __align__(16) short hhi[2][4][64][8];  // h hi frags (sigma slots)
    __shared__ __align__(16) short hlo[2][4][64][8];  // h lo frags (sigma slots)
    __shared__ int cix[MB][KK];

    // ---- B-fragments (weights, RNE bf16) resident in VGPRs.
    short8 wbi[3][4], wbh[3][4];
#pragma unroll
    for (int tt = 0; tt < 3; ++tt) {
        const int g = (w + 8 * tt) * 16 + nl;
#pragma unroll
        for (int c = 0; c < 4; ++c) {
            const float* wi = w_ih + (size_t)g * FF + c * 32 + q * 8;
            const float* wh = w_hh + (size_t)g * FF + c * 32 + q * 8;
            short8 a, b;
#pragma unroll
            for (int j = 0; j < 8; ++j) { a[j] = bf_rne(wi[j]); b[j] = bf_rne(wh[j]); }
            wbi[tt][c] = a; wbh[tt][c] = b;
        }
    }
    const int fcol = w * 16 + nl;
    const float bR  = b_ih[fcol] + b_hh[fcol];
    const float bZ  = b_ih[FF + fcol] + b_hh[FF + fcol];
    const float bNi = b_ih[2 * FF + fcol];
    const float bNh = b_hh[2 * FF + fcol];

    if (tid < MB * KK) cix[tid >> 3][tid & 7] = idx[(p0 + (tid >> 3)) * KK + (tid & 7)];
    __syncthreads();  // cix ready for stagers

    // ---- producer-side h-frag indices (this lane's column f = fcol)
    const int qqF = (2 * (w & 1) + (nl >> 3)) & 3;
    const int jF  = nl & 7;
    const int cF  = w >> 1;
    // consumer-side sigma slot for this lane's A-frag reads
    const int qqC = lane >> 4;
    const int scn = ((lane >> 2) & 3) + 4 * ((lane & 3) ^ qqC) + 16 * qqC;

    // ---- h0: f32 master in regs + hi/lo frags into buf0
    float hm[4];
#pragma unroll
    for (int r = 0; r < 4; ++r) {
        const float h = h0[(size_t)(p0 + 4 * q + r) * FF + fcol];
        hm[r] = h;
        const uint32_t u  = fbits(h);
        const int sp = q + 4 * (r ^ qqF) + 16 * qqF;
        hhi[0][cF][sp][jF] = (short)(u >> 16);
        const float lo = h - bitsf(u & 0xffff0000u);
        hlo[0][cF][sp][jF] = (short)(fbits(lo) >> 16);
    }

    // ---- x stager mapping: thread handles half a frag row
    const int c_s    = tid >> 7;
    const int slot_s = (tid >> 1) & 63;
    const int half   = tid & 1;
    const int m_s    = slot_s & 15;
    const int qq_s   = slot_s >> 4;
    const int k0s    = c_s * 32 + qq_s * 8 + 4 * half;

    // stage x_0 into buf0
    {
        const int ch = cix[m_s][0];
        const float4 v = *(const float4*)(feat + (size_t)ch * (TT * FF) + k0s);
        uint2 pkd = { pk_trunc(v.x, v.y), pk_trunc(v.z, v.w) };
        *(uint2*)&xfr[0][c_s][slot_s][4 * half] = pkd;
    }
    // prefetch x_1
    float4 xp;
    {
        const int ch = cix[m_s][0];
        xp = *(const float4*)(feat + (size_t)ch * (TT * FF) + FF + k0s);
    }
    __syncthreads();

    int curb = 0;
    for (int s = 0; s < NSTEP; ++s) {
        const int nxtb = curb ^ 1;

        // stage x_{s+1} (loaded last iter) into next buffer
        if (s < NSTEP - 1) {
            uint2 pkd = { pk_trunc(xp.x, xp.y), pk_trunc(xp.z, xp.w) };
            *(uint2*)&xfr[nxtb][c_s][slot_s][4 * half] = pkd;
        }
        // prefetch x_{s+2} (fully latency-hidden behind this step)
        if (s < NSTEP - 2) {
            const int u = s + 2;
            const int ch = cix[m_s][u >> 5];
            xp = *(const float4*)(feat + (size_t)ch * (TT * FF) + (u & 31) * FF + k0s);
        }

        // A-frags (all reads conflict-free b128)
        short8 xa[4], ha[4], la[4];
#pragma unroll
        for (int c = 0; c < 4; ++c) {
            xa[c] = *(const short8*)&xfr[curb][c][lane][0];
            ha[c] = *(const short8*)&hhi[curb][c][scn][0];
            la[c] = *(const short8*)&hlo[curb][c][scn][0];
        }

        f32x4 ax[3], ah[3];
#pragma unroll
        for (int tt = 0; tt < 3; ++tt) {
            f32x4 a = {0.f, 0.f, 0.f, 0.f};
            f32x4 u = {0.f, 0.f, 0.f, 0.f};
            f32x4 v = {0.f, 0.f, 0.f, 0.f};
#pragma unroll
            for (int c = 0; c < 4; ++c)
                a = __builtin_amdgcn_mfma_f32_16x16x32_bf16(xa[c], wbi[tt][c], a, 0, 0, 0);
#pragma unroll
            for (int c = 0; c < 4; ++c)
                u = __builtin_amdgcn_mfma_f32_16x16x32_bf16(ha[c], wbh[tt][c], u, 0, 0, 0);
#pragma unroll
            for (int c = 0; c < 4; ++c)
                v = __builtin_amdgcn_mfma_f32_16x16x32_bf16(la[c], wbh[tt][c], v, 0, 0, 0);
            ax[tt] = a; ah[tt] = u + v;
        }

        // gates + state update; lane owns rows m=4q+r at column fcol
#pragma unroll
        for (int r = 0; r < 4; ++r) {
            const float rg = sigm(ax[0][r] + ah[0][r] + bR);
            const float zg = sigm(ax[1][r] + ah[1][r] + bZ);
            const float np = ax[2][r] + bNi + rg * (ah[2][r] + bNh);
            const float ng = tanh_fast(np);
            const float h  = ng + zg * (hm[r] - ng);
            hm[r] = h;
            const uint32_t uu = fbits(h);
            const int sp = q + 4 * (r ^ qqF) + 16 * qqF;
            hhi[nxtb][cF][sp][jF] = (short)(uu >> 16);
            const float lo = h - bitsf(uu & 0xffff0000u);
            hlo[nxtb][cF][sp][jF] = (short)(fbits(lo) >> 16);
        }
        __syncthreads();
        curb = nxtb;
    }

    // final h straight from registers
#pragma unroll
    for (int r = 0; r < 4; ++r)
        out[(size_t)(p0 + 4 * q + r) * FF + fcol] = hm[r];
}

extern "C" void kernel_launch(void* const* d_in, const int* in_sizes, int n_in,
                              void* d_out, int out_size, void* d_ws, size_t ws_size,
                              hipStream_t stream) {
    const float* h0   = (const float*)d_in[0];
    const float* feat = (const float*)d_in[1];
    const float* wih  = (const float*)d_in[2];
    const float* whh  = (const float*)d_in[3];
    const float* bih  = (const float*)d_in[4];
    const float* bhh  = (const float*)d_in[5];
    const int*   idx  = (const int*)d_in[6];
    float*       out  = (float*)d_out;

    gru_mfma2<<<dim3(NBLK), dim3(NTHR), 0, stream>>>(
        h0, feat, wih, whh, bih, bhh, idx, out);
}

// Round 5
// 562.012 us; speedup vs baseline: 18.5074x; 1.0311x over previous
//
#include <hip/hip_runtime.h>
#include <cstdint>
#include <cstddef>

// Problem constants: P=2048, K=8, T=32, C=16384, F=128
#define PP 2048
#define KK 8
#define TT 32
#define FF 128
#define MB 16
#define NBLK (PP/MB)
#define NTHR 512
#define NSTEP (KK*TT)

typedef __attribute__((ext_vector_type(8))) short short8;  // 8 bf16 (4 VGPRs)
typedef __attribute__((ext_vector_type(4))) float f32x4;   // MFMA C/D frag

__device__ __forceinline__ uint32_t fbits(float x){ union{float f;uint32_t u;}c;c.f=x;return c.u; }
// f32 -> bf16 bits, round-to-nearest-even (3-4 VALU ops)
__device__ __forceinline__ uint32_t rne16(uint32_t u){
    return (u + 0x7fffu + ((u >> 16) & 1u)) >> 16;
}
__device__ __forceinline__ short bf_rne(float x){ return (short)rne16(fbits(x)); }
__device__ __forceinline__ uint32_t pk_rne(float a, float b){
    return rne16(fbits(a)) | (rne16(fbits(b)) << 16);
}
__device__ __forceinline__ float sigm(float x){
    float t = __expf(-x);                    // x->-inf: t=inf -> rcp=0; x->inf: t=0 -> 1
    return __builtin_amdgcn_rcpf(1.f + t);
}
__device__ __forceinline__ float tanh_fast(float x){
    float e = __expf(-2.f * x);              // saturates correctly via inf -> rcp -> 0
    return __builtin_amdgcn_rcpf(1.f + e) * 2.f - 1.f;
}

// Block: 16 paths x 256 GRU steps. 8 waves; wave w owns gate columns
// f in [16w,16w+16) (tiles {w,w+8,w+16} = r,z,n). Weights resident in VGPRs
// as MFMA B-fragments. h f32 master lives in the producing lane's VGPRs;
// h crosses waves as SINGLE RNE-bf16 fragments via LDS (lo-term dropped:
// -33% LDS A-traffic, -33% MFMA, shorter chain; RNE not trunc so the
// per-step quantization is unbiased and the z-blend contracts it).
// Sigma-swizzled h layout (slot = q + 4*(r^qq) + 16*qq): producer b16
// scatter ~2-way (free), consumer ds_read_b128 conflict-free.
// x staged pre-converted (RNE) into frag layout with one-step-ahead global
// prefetch. One barrier per step.
__global__ __launch_bounds__(NTHR, 2) void gru_mfma3(
    const float* __restrict__ h0,    // [P, F]
    const float* __restrict__ feat,  // [C, T, F]
    const float* __restrict__ w_ih,  // [3F, F]
    const float* __restrict__ w_hh,  // [3F, F]
    const float* __restrict__ b_ih,  // [3F]
    const float* __restrict__ b_hh,  // [3F]
    const int* __restrict__ idx,     // [P, K]
    float* __restrict__ out)         // [P, F]
{
    const int tid  = threadIdx.x;
    const int w    = tid >> 6;
    const int lane = tid & 63;
    const int q    = lane >> 4;
    const int nl   = lane & 15;
    const int p0   = blockIdx.x * MB;

    __shared__ __align__(16) short xfr[2][4][64][8];  // x frags (identity slots)
    __shared__ __align__(16) short hhi[2][4][64][8];  // h frags (sigma slots)
    __shared__ int cix[MB][KK];

    // ---- B-fragments (weights, RNE bf16) resident in VGPRs.
    short8 wbi[3][4], wbh[3][4];
#pragma unroll
    for (int tt = 0; tt < 3; ++tt) {
        const int g = (w + 8 * tt) * 16 + nl;
#pragma unroll
        for (int c = 0; c < 4; ++c) {
            const float* wi = w_ih + (size_t)g * FF + c * 32 + q * 8;
            const float* wh = w_hh + (size_t)g * FF + c * 32 + q * 8;
            short8 a, b;
#pragma unroll
            for (int j = 0; j < 8; ++j) { a[j] = bf_rne(wi[j]); b[j] = bf_rne(wh[j]); }
            wbi[tt][c] = a; wbh[tt][c] = b;
        }
    }
    const int fcol = w * 16 + nl;
    const float bR  = b_ih[fcol] + b_hh[fcol];
    const float bZ  = b_ih[FF + fcol] + b_hh[FF + fcol];
    const float bNi = b_ih[2 * FF + fcol];
    const float bNh = b_hh[2 * FF + fcol];

    if (tid < MB * KK) cix[tid >> 3][tid & 7] = idx[(p0 + (tid >> 3)) * KK + (tid & 7)];
    __syncthreads();  // cix ready for stagers

    // ---- producer-side h-frag indices (this lane's column f = fcol)
    const int qqF = (2 * (w & 1) + (nl >> 3)) & 3;
    const int jF  = nl & 7;
    const int cF  = w >> 1;
    // consumer-side sigma slot for this lane's A-frag reads
    const int qqC = lane >> 4;
    const int scn = ((lane >> 2) & 3) + 4 * ((lane & 3) ^ qqC) + 16 * qqC;

    // ---- h0: f32 master in regs + RNE bf16 frags into buf0
    float hm[4];
#pragma unroll
    for (int r = 0; r < 4; ++r) {
        const float h = h0[(size_t)(p0 + 4 * q + r) * FF + fcol];
        hm[r] = h;
        const int sp = q + 4 * (r ^ qqF) + 16 * qqF;
        hhi[0][cF][sp][jF] = bf_rne(h);
    }

    // ---- x stager mapping: thread handles half a frag row
    const int c_s    = tid >> 7;
    const int slot_s = (tid >> 1) & 63;
    const int half   = tid & 1;
    const int m_s    = slot_s & 15;
    const int qq_s   = slot_s >> 4;
    const int k0s    = c_s * 32 + qq_s * 8 + 4 * half;

    // stage x_0 into buf0
    {
        const int ch = cix[m_s][0];
        const float4 v = *(const float4*)(feat + (size_t)ch * (TT * FF) + k0s);
        uint2 pkd = { pk_rne(v.x, v.y), pk_rne(v.z, v.w) };
        *(uint2*)&xfr[0][c_s][slot_s][4 * half] = pkd;
    }
    // prefetch x_1
    float4 xp;
    {
        const int ch = cix[m_s][0];
        xp = *(const float4*)(feat + (size_t)ch * (TT * FF) + FF + k0s);
    }
    __syncthreads();

    int curb = 0;
    for (int s = 0; s < NSTEP; ++s) {
        const int nxtb = curb ^ 1;

        // stage x_{s+1} (loaded last iter) into next buffer
        if (s < NSTEP - 1) {
            uint2 pkd = { pk_rne(xp.x, xp.y), pk_rne(xp.z, xp.w) };
            *(uint2*)&xfr[nxtb][c_s][slot_s][4 * half] = pkd;
        }
        // prefetch x_{s+2} (fully latency-hidden behind this step)
        if (s < NSTEP - 2) {
            const int u = s + 2;
            const int ch = cix[m_s][u >> 5];
            xp = *(const float4*)(feat + (size_t)ch * (TT * FF) + (u & 31) * FF + k0s);
        }

        // A-frags (all reads conflict-free b128): 8 per lane (x + h)
        short8 xa[4], ha[4];
#pragma unroll
        for (int c = 0; c < 4; ++c) {
            xa[c] = *(const short8*)&xfr[curb][c][lane][0];
            ha[c] = *(const short8*)&hhi[curb][c][scn][0];
        }

        f32x4 ax[3], ah[3];
#pragma unroll
        for (int tt = 0; tt < 3; ++tt) {
            // split 2+2 for FMA-chain ILP
            f32x4 a0 = {0.f,0.f,0.f,0.f}, a1 = {0.f,0.f,0.f,0.f};
            f32x4 u0 = {0.f,0.f,0.f,0.f}, u1 = {0.f,0.f,0.f,0.f};
            a0 = __builtin_amdgcn_mfma_f32_16x16x32_bf16(xa[0], wbi[tt][0], a0, 0, 0, 0);
            a0 = __builtin_amdgcn_mfma_f32_16x16x32_bf16(xa[1], wbi[tt][1], a0, 0, 0, 0);
            a1 = __builtin_amdgcn_mfma_f32_16x16x32_bf16(xa[2], wbi[tt][2], a1, 0, 0, 0);
            a1 = __builtin_amdgcn_mfma_f32_16x16x32_bf16(xa[3], wbi[tt][3], a1, 0, 0, 0);
            u0 = __builtin_amdgcn_mfma_f32_16x16x32_bf16(ha[0], wbh[tt][0], u0, 0, 0, 0);
            u0 = __builtin_amdgcn_mfma_f32_16x16x32_bf16(ha[1], wbh[tt][1], u0, 0, 0, 0);
            u1 = __builtin_amdgcn_mfma_f32_16x16x32_bf16(ha[2], wbh[tt][2], u1, 0, 0, 0);
            u1 = __builtin_amdgcn_mfma_f32_16x16x32_bf16(ha[3], wbh[tt][3], u1, 0, 0, 0);
            ax[tt] = a0 + a1; ah[tt] = u0 + u1;
        }

        // gates + state update; lane owns rows m=4q+r at column fcol
#pragma unroll
        for (int r = 0; r < 4; ++r) {
            const float rg = sigm(ax[0][r] + ah[0][r] + bR);
            const float zg = sigm(ax[1][r] + ah[1][r] + bZ);
            const float np = ax[2][r] + bNi + rg * (ah[2][r] + bNh);
            const float ng = tanh_fast(np);
            const float h  = ng + zg * (hm[r] - ng);
            hm[r] = h;
            const int sp = q + 4 * (r ^ qqF) + 16 * qqF;
            hhi[nxtb][cF][sp][jF] = bf_rne(h);
        }
        __syncthreads();
        curb = nxtb;
    }

    // final h straight from registers
#pragma unroll
    for (int r = 0; r < 4; ++r)
        out[(size_t)(p0 + 4 * q + r) * FF + fcol] = hm[r];
}

extern "C" void kernel_launch(void* const* d_in, const int* in_sizes, int n_in,
                              void* d_out, int out_size, void* d_ws, size_t ws_size,
                              hipStream_t stream) {
    const float* h0   = (const float*)d_in[0];
    const float* feat = (const float*)d_in[1];
    const float* wih  = (const float*)d_in[2];
    const float* whh  = (const float*)d_in[3];
    const float* bih  = (const float*)d_in[4];
    const float* bhh  = (const float*)d_in[5];
    const int*   idx  = (const int*)d_in[6];
    float*       out  = (float*)d_out;

    gru_mfma3<<<dim3(NBLK), dim3(NTHR), 0, stream>>>(
        h0, feat, wih, whh, bih, bhh, idx, out);
}